// Round 1
// baseline (730.175 us; speedup 1.0000x reference)
//
#include <hip/hip_runtime.h>

// 3D LUT trilinear interpolation, fp32.
// rgb: (2,2160,3840,3) f32, lut: (65,65,65,3) f32, out: same shape as rgb.

static constexpr int S  = 65;
static constexpr int S2 = S * S;       // 4225
static constexpr int SN = S * S * S;   // 274625

// ---------- LUT padding: 3 floats/entry -> float4/entry in d_ws ----------
__global__ __launch_bounds__(256) void pad_lut(const float* __restrict__ lut,
                                               float4* __restrict__ plut) {
    int i = blockIdx.x * blockDim.x + threadIdx.x;
    if (i < SN) {
        plut[i] = make_float4(lut[3 * i + 0], lut[3 * i + 1], lut[3 * i + 2], 0.0f);
    }
}

// ---------- corner fetch (padded float4 path or raw 3-float path) ----------
template <bool PADDED>
__device__ __forceinline__ void fetch_corner(const void* __restrict__ lutp, int idx,
                                             float& r, float& g, float& b) {
    if constexpr (PADDED) {
        float4 v = ((const float4*)lutp)[idx];
        r = v.x; g = v.y; b = v.z;
    } else {
        const float* p = (const float*)lutp + 3 * idx;
        r = p[0]; g = p[1]; b = p[2];
    }
}

// ---------- one pixel: faithful to reference op order ----------
template <bool PADDED>
__device__ __forceinline__ void lut_pixel(float r, float g, float b,
                                          const void* __restrict__ lutp,
                                          float& o0, float& o1, float& o2) {
    // coords = rgb * (S-1); frac from UNCLAMPED floor; index from clamped floor.
    float cx = r * 64.0f, cy = g * 64.0f, cz = b * 64.0f;
    float fx = floorf(cx), fy = floorf(cy), fz = floorf(cz);
    float wx = cx - fx, wy = cy - fy, wz = cz - fz;
    int x = (int)fx, y = (int)fy, z = (int)fz;
    x = x < 0 ? 0 : (x > S - 2 ? S - 2 : x);
    y = y < 0 ? 0 : (y > S - 2 ? S - 2 : y);
    z = z < 0 ? 0 : (z > S - 2 ? S - 2 : z);
    int base = x * S2 + y * S + z;

    const int offs[8] = {0, 1, S, S + 1, S2, S2 + 1, S2 + S, S2 + S + 1};
    float c[8][3];
#pragma unroll
    for (int k = 0; k < 8; ++k) {
        fetch_corner<PADDED>(lutp, base + offs[k], c[k][0], c[k][1], c[k][2]);
    }

    float iz = 1.0f - wz, iy = 1.0f - wy, ix = 1.0f - wx;
    float o[3];
#pragma unroll
    for (int ch = 0; ch < 3; ++ch) {
        float v00 = c[0][ch] * iz + c[1][ch] * wz;
        float v01 = c[2][ch] * iz + c[3][ch] * wz;
        float v10 = c[4][ch] * iz + c[5][ch] * wz;
        float v11 = c[6][ch] * iz + c[7][ch] * wz;
        float v0 = v00 * iy + v01 * wy;
        float v1 = v10 * iy + v11 * wy;
        o[ch] = v0 * ix + v1 * wx;
    }
    o0 = o[0]; o1 = o[1]; o2 = o[2];
}

// ---------- main kernel: 4 pixels / thread via 3x float4 ----------
template <bool PADDED>
__global__ __launch_bounds__(256) void lut3d_apply(const float* __restrict__ rgb,
                                                   const void* __restrict__ lutp,
                                                   float* __restrict__ out,
                                                   int ngroups) {
    int t = blockIdx.x * blockDim.x + threadIdx.x;
    if (t >= ngroups) return;
    const float4* __restrict__ in4 = (const float4*)rgb;
    float4* __restrict__ out4 = (float4*)out;
    size_t b = (size_t)t * 3;
    float4 A = in4[b + 0];
    float4 B = in4[b + 1];
    float4 C = in4[b + 2];

    float px[4][3] = {{A.x, A.y, A.z}, {A.w, B.x, B.y}, {B.z, B.w, C.x}, {C.y, C.z, C.w}};
    float o[4][3];
#pragma unroll
    for (int p = 0; p < 4; ++p) {
        lut_pixel<PADDED>(px[p][0], px[p][1], px[p][2], lutp, o[p][0], o[p][1], o[p][2]);
    }

    out4[b + 0] = make_float4(o[0][0], o[0][1], o[0][2], o[1][0]);
    out4[b + 1] = make_float4(o[1][1], o[1][2], o[2][0], o[2][1]);
    out4[b + 2] = make_float4(o[2][2], o[3][0], o[3][1], o[3][2]);
}

// ---------- scalar tail (pixels not covered by 4-pixel groups) ----------
template <bool PADDED>
__global__ void lut3d_tail(const float* __restrict__ rgb,
                           const void* __restrict__ lutp,
                           float* __restrict__ out,
                           int start_pix, int npix) {
    int i = start_pix + blockIdx.x * blockDim.x + threadIdx.x;
    if (i >= npix) return;
    float o0, o1, o2;
    lut_pixel<PADDED>(rgb[3 * i + 0], rgb[3 * i + 1], rgb[3 * i + 2], lutp, o0, o1, o2);
    out[3 * i + 0] = o0;
    out[3 * i + 1] = o1;
    out[3 * i + 2] = o2;
}

extern "C" void kernel_launch(void* const* d_in, const int* in_sizes, int n_in,
                              void* d_out, int out_size, void* d_ws, size_t ws_size,
                              hipStream_t stream) {
    const float* rgb = (const float*)d_in[0];
    const float* lut = (const float*)d_in[1];
    float* out = (float*)d_out;

    int n = in_sizes[0];         // total floats in rgb
    int npix = n / 3;
    int groups = npix / 4;       // 4 pixels per thread
    int rem = npix - groups * 4;

    const bool padded = ws_size >= (size_t)SN * sizeof(float4);

    if (padded) {
        float4* plut = (float4*)d_ws;
        pad_lut<<<(SN + 255) / 256, 256, 0, stream>>>(lut, plut);
        if (groups)
            lut3d_apply<true><<<(groups + 255) / 256, 256, 0, stream>>>(rgb, plut, out, groups);
        if (rem)
            lut3d_tail<true><<<1, 64, 0, stream>>>(rgb, plut, out, npix - rem, npix);
    } else {
        if (groups)
            lut3d_apply<false><<<(groups + 255) / 256, 256, 0, stream>>>(rgb, lut, out, groups);
        if (rem)
            lut3d_tail<false><<<1, 64, 0, stream>>>(rgb, lut, out, npix - rem, npix);
    }
}

// Round 2
// 576.418 us; speedup vs baseline: 1.2667x; 1.2667x over previous
//
#include <hip/hip_runtime.h>
#include <hip/hip_fp16.h>

// Trilinear 3D LUT, fp32 in/out.
// rgb: (2,2160,3840,3) f32, lut: (65,65,65,3) f32, out same as rgb.
//
// Strategy: per-call, expand the 65^3x3 f32 LUT into a 64^3 "cube table":
// each record holds all 8 corners x 3 channels in fp16 (48 B), padded to a
// 64 B-aligned record. Main kernel: ONE random cache line per pixel
// (3x global_load_dwordx4 from the same line), fp32 lerp chain.

static constexpr int S  = 65;
static constexpr int S2 = S * S;           // 4225
static constexpr int SN = S * S * S;       // 274625
static constexpr int CN = 64 * 64 * 64;    // 262144 cube records
static constexpr size_t CUBE_BYTES = (size_t)CN * 64;   // 16 MiB

// ---------------- half helpers ----------------
__device__ __forceinline__ unsigned int pk2h(float a, float b) {
    __half2 h = __floats2half2_rn(a, b);
    return *reinterpret_cast<unsigned int*>(&h);
}
__device__ __forceinline__ float2 up2f(unsigned int u) {
    __half2 h = *reinterpret_cast<const __half2*>(&u);
    return __half22float2(h);
}

// ---------------- cube build: (x,y,z) in [0,63]^3 ----------------
// record layout (16 u32): slot = ch*4 + dx*2 + dy; u32 = (half(z0), half(z1)).
// slots 12..15 = pad.
__global__ __launch_bounds__(256) void build_cube(const float* __restrict__ lut,
                                                  uint4* __restrict__ cube) {
    int id = blockIdx.x * blockDim.x + threadIdx.x;
    if (id >= CN) return;
    int z = id & 63, y = (id >> 6) & 63, x = id >> 12;

    unsigned int w[16];
#pragma unroll
    for (int ch = 0; ch < 3; ++ch) {
#pragma unroll
        for (int dx = 0; dx < 2; ++dx) {
#pragma unroll
            for (int dy = 0; dy < 2; ++dy) {
                int base = ((x + dx) * S2 + (y + dy) * S + z) * 3 + ch;
                float a = lut[base];          // z
                float b = lut[base + 3];      // z+1
                w[ch * 4 + dx * 2 + dy] = pk2h(a, b);
            }
        }
    }
    w[12] = w[13] = w[14] = w[15] = 0u;

    uint4* rp = cube + (size_t)id * 4;
    rp[0] = make_uint4(w[0], w[1], w[2], w[3]);
    rp[1] = make_uint4(w[4], w[5], w[6], w[7]);
    rp[2] = make_uint4(w[8], w[9], w[10], w[11]);
    rp[3] = make_uint4(w[12], w[13], w[14], w[15]);
}

// ---------------- per-channel trilinear from one quarter-record ----------------
__device__ __forceinline__ float tri_ch(uint4 q, float iz, float wz,
                                        float iy, float wy, float ix, float wx) {
    float2 a = up2f(q.x);  // (dx0,dy0): z0,z1
    float2 b = up2f(q.y);  // (dx0,dy1)
    float2 c = up2f(q.z);  // (dx1,dy0)
    float2 d = up2f(q.w);  // (dx1,dy1)
    float v00 = a.x * iz + a.y * wz;
    float v01 = b.x * iz + b.y * wz;
    float v10 = c.x * iz + c.y * wz;
    float v11 = d.x * iz + d.y * wz;
    float v0 = v00 * iy + v01 * wy;
    float v1 = v10 * iy + v11 * wy;
    return v0 * ix + v1 * wx;
}

__device__ __forceinline__ void lut_pixel_cube(float r, float g, float b,
                                               const uint4* __restrict__ cube,
                                               float& o0, float& o1, float& o2) {
    float cx = r * 64.0f, cy = g * 64.0f, cz = b * 64.0f;
    float fx = floorf(cx), fy = floorf(cy), fz = floorf(cz);
    float wx = cx - fx, wy = cy - fy, wz = cz - fz;
    int x = (int)fx, y = (int)fy, z = (int)fz;
    x = x < 0 ? 0 : (x > 63 ? 63 : x);
    y = y < 0 ? 0 : (y > 63 ? 63 : y);
    z = z < 0 ? 0 : (z > 63 ? 63 : z);
    unsigned int rec = ((unsigned)x << 12) | ((unsigned)y << 6) | (unsigned)z;
    const uint4* rp = cube + (size_t)rec * 4;
    uint4 qr = rp[0];
    uint4 qg = rp[1];
    uint4 qb = rp[2];   // 4th quarter (pad) never loaded: 48 B from one 64 B line
    float iz = 1.0f - wz, iy = 1.0f - wy, ix = 1.0f - wx;
    o0 = tri_ch(qr, iz, wz, iy, wy, ix, wx);
    o1 = tri_ch(qg, iz, wz, iy, wy, ix, wx);
    o2 = tri_ch(qb, iz, wz, iy, wy, ix, wx);
}

// ---------------- main: 4 pixels / thread via 3x float4 ----------------
__global__ __launch_bounds__(256) void lut3d_cube_apply(const float* __restrict__ rgb,
                                                        const uint4* __restrict__ cube,
                                                        float* __restrict__ out,
                                                        int ngroups) {
    int t = blockIdx.x * blockDim.x + threadIdx.x;
    if (t >= ngroups) return;
    const float4* __restrict__ in4 = (const float4*)rgb;
    float4* __restrict__ out4 = (float4*)out;
    size_t b = (size_t)t * 3;
    float4 A = in4[b + 0];
    float4 B = in4[b + 1];
    float4 C = in4[b + 2];

    float px[4][3] = {{A.x, A.y, A.z}, {A.w, B.x, B.y}, {B.z, B.w, C.x}, {C.y, C.z, C.w}};
    float o[4][3];
#pragma unroll
    for (int p = 0; p < 4; ++p) {
        lut_pixel_cube(px[p][0], px[p][1], px[p][2], cube, o[p][0], o[p][1], o[p][2]);
    }

    out4[b + 0] = make_float4(o[0][0], o[0][1], o[0][2], o[1][0]);
    out4[b + 1] = make_float4(o[1][1], o[1][2], o[2][0], o[2][1]);
    out4[b + 2] = make_float4(o[2][2], o[3][0], o[3][1], o[3][2]);
}

__global__ void lut3d_cube_tail(const float* __restrict__ rgb,
                                const uint4* __restrict__ cube,
                                float* __restrict__ out,
                                int start_pix, int npix) {
    int i = start_pix + blockIdx.x * blockDim.x + threadIdx.x;
    if (i >= npix) return;
    float o0, o1, o2;
    lut_pixel_cube(rgb[3 * i + 0], rgb[3 * i + 1], rgb[3 * i + 2], cube, o0, o1, o2);
    out[3 * i + 0] = o0;
    out[3 * i + 1] = o1;
    out[3 * i + 2] = o2;
}

// ================= fallback path (round-1 kernel, padded float4 LUT) =================
__global__ __launch_bounds__(256) void pad_lut(const float* __restrict__ lut,
                                               float4* __restrict__ plut) {
    int i = blockIdx.x * blockDim.x + threadIdx.x;
    if (i < SN) {
        plut[i] = make_float4(lut[3 * i + 0], lut[3 * i + 1], lut[3 * i + 2], 0.0f);
    }
}

template <bool PADDED>
__device__ __forceinline__ void fetch_corner(const void* __restrict__ lutp, int idx,
                                             float& r, float& g, float& b) {
    if constexpr (PADDED) {
        float4 v = ((const float4*)lutp)[idx];
        r = v.x; g = v.y; b = v.z;
    } else {
        const float* p = (const float*)lutp + 3 * idx;
        r = p[0]; g = p[1]; b = p[2];
    }
}

template <bool PADDED>
__device__ __forceinline__ void lut_pixel(float r, float g, float b,
                                          const void* __restrict__ lutp,
                                          float& o0, float& o1, float& o2) {
    float cx = r * 64.0f, cy = g * 64.0f, cz = b * 64.0f;
    float fx = floorf(cx), fy = floorf(cy), fz = floorf(cz);
    float wx = cx - fx, wy = cy - fy, wz = cz - fz;
    int x = (int)fx, y = (int)fy, z = (int)fz;
    x = x < 0 ? 0 : (x > S - 2 ? S - 2 : x);
    y = y < 0 ? 0 : (y > S - 2 ? S - 2 : y);
    z = z < 0 ? 0 : (z > S - 2 ? S - 2 : z);
    int base = x * S2 + y * S + z;

    const int offs[8] = {0, 1, S, S + 1, S2, S2 + 1, S2 + S, S2 + S + 1};
    float c[8][3];
#pragma unroll
    for (int k = 0; k < 8; ++k)
        fetch_corner<PADDED>(lutp, base + offs[k], c[k][0], c[k][1], c[k][2]);

    float iz = 1.0f - wz, iy = 1.0f - wy, ix = 1.0f - wx;
    float o[3];
#pragma unroll
    for (int ch = 0; ch < 3; ++ch) {
        float v00 = c[0][ch] * iz + c[1][ch] * wz;
        float v01 = c[2][ch] * iz + c[3][ch] * wz;
        float v10 = c[4][ch] * iz + c[5][ch] * wz;
        float v11 = c[6][ch] * iz + c[7][ch] * wz;
        float v0 = v00 * iy + v01 * wy;
        float v1 = v10 * iy + v11 * wy;
        o[ch] = v0 * ix + v1 * wx;
    }
    o0 = o[0]; o1 = o[1]; o2 = o[2];
}

template <bool PADDED>
__global__ __launch_bounds__(256) void lut3d_apply(const float* __restrict__ rgb,
                                                   const void* __restrict__ lutp,
                                                   float* __restrict__ out,
                                                   int ngroups) {
    int t = blockIdx.x * blockDim.x + threadIdx.x;
    if (t >= ngroups) return;
    const float4* __restrict__ in4 = (const float4*)rgb;
    float4* __restrict__ out4 = (float4*)out;
    size_t b = (size_t)t * 3;
    float4 A = in4[b + 0];
    float4 B = in4[b + 1];
    float4 C = in4[b + 2];

    float px[4][3] = {{A.x, A.y, A.z}, {A.w, B.x, B.y}, {B.z, B.w, C.x}, {C.y, C.z, C.w}};
    float o[4][3];
#pragma unroll
    for (int p = 0; p < 4; ++p)
        lut_pixel<PADDED>(px[p][0], px[p][1], px[p][2], lutp, o[p][0], o[p][1], o[p][2]);

    out4[b + 0] = make_float4(o[0][0], o[0][1], o[0][2], o[1][0]);
    out4[b + 1] = make_float4(o[1][1], o[1][2], o[2][0], o[2][1]);
    out4[b + 2] = make_float4(o[2][2], o[3][0], o[3][1], o[3][2]);
}

template <bool PADDED>
__global__ void lut3d_tail(const float* __restrict__ rgb,
                           const void* __restrict__ lutp,
                           float* __restrict__ out,
                           int start_pix, int npix) {
    int i = start_pix + blockIdx.x * blockDim.x + threadIdx.x;
    if (i >= npix) return;
    float o0, o1, o2;
    lut_pixel<PADDED>(rgb[3 * i + 0], rgb[3 * i + 1], rgb[3 * i + 2], lutp, o0, o1, o2);
    out[3 * i + 0] = o0;
    out[3 * i + 1] = o1;
    out[3 * i + 2] = o2;
}

extern "C" void kernel_launch(void* const* d_in, const int* in_sizes, int n_in,
                              void* d_out, int out_size, void* d_ws, size_t ws_size,
                              hipStream_t stream) {
    const float* rgb = (const float*)d_in[0];
    const float* lut = (const float*)d_in[1];
    float* out = (float*)d_out;

    int n = in_sizes[0];
    int npix = n / 3;
    int groups = npix / 4;
    int rem = npix - groups * 4;

    if (ws_size >= CUBE_BYTES) {
        uint4* cube = (uint4*)d_ws;
        build_cube<<<(CN + 255) / 256, 256, 0, stream>>>(lut, cube);
        if (groups)
            lut3d_cube_apply<<<(groups + 255) / 256, 256, 0, stream>>>(rgb, cube, out, groups);
        if (rem)
            lut3d_cube_tail<<<1, 64, 0, stream>>>(rgb, cube, out, npix - rem, npix);
    } else if (ws_size >= (size_t)SN * sizeof(float4)) {
        float4* plut = (float4*)d_ws;
        pad_lut<<<(SN + 255) / 256, 256, 0, stream>>>(lut, plut);
        if (groups)
            lut3d_apply<true><<<(groups + 255) / 256, 256, 0, stream>>>(rgb, plut, out, groups);
        if (rem)
            lut3d_tail<true><<<1, 64, 0, stream>>>(rgb, plut, out, npix - rem, npix);
    } else {
        if (groups)
            lut3d_apply<false><<<(groups + 255) / 256, 256, 0, stream>>>(rgb, lut, out, groups);
        if (rem)
            lut3d_tail<false><<<1, 64, 0, stream>>>(rgb, lut, out, npix - rem, npix);
    }
}